// Round 1
// baseline (71.198 us; speedup 1.0000x reference)
//
#include <hip/hip_runtime.h>

// HungarianMatcher cost kernel.
// C[q,t] = sum_d mask[t,d]*|kp[q,d]-tgt[t,d]| + (pos-neg)[q, ids[t]]
// Q=16384, T=64, D=63, C=2 classes.
//
// Design: GEMM-style tiling. Block = 64q x 64t (all targets), 256 threads,
// thread tile 4q x 4t. LDS holds transposed [d][q] / [d][t] tiles with
// pitch 68 floats (17 float4) -> conflict-free b128 reads in the main loop.
// mask staged as 0/1 float so inner op is v_sub + v_fma(abs) = 2 VALU/elem.

#define ALPHA 0.25f
#define EPS 1e-8f

constexpr int Q  = 16 * 1024;  // bs*nq
constexpr int T  = 64;
constexpr int D  = 63;
constexpr int QB = 64;         // q rows per block
constexpr int P  = 68;         // LDS pitch in floats (17 float4s)
constexpr int P4 = 17;

__device__ inline float focal_cost(float x) {
  float p   = 1.0f / (1.0f + __expf(-x));
  float pos = ALPHA * (1.0f - p) * (1.0f - p) * (-__logf(p + EPS));
  float neg = (1.0f - ALPHA) * p * p * (-__logf(1.0f - p + EPS));
  return pos - neg;
}

__global__ __launch_bounds__(256) void matcher_kernel(
    const float* __restrict__ logits,  // [Q,2]
    const float* __restrict__ kp,      // [Q,63]
    const float* __restrict__ tgt,     // [64,63]
    const int*   __restrict__ ids,     // [64]
    float* __restrict__ out)           // [Q,64]
{
  __shared__ __align__(16) float As[64 * P];  // [d][q]  (row d, col q)
  __shared__ __align__(16) float Bv[64 * P];  // [d][t]
  __shared__ __align__(16) float Bm[64 * P];  // [d][t] mask 0/1
  __shared__ int Ids[T];

  const int tid   = threadIdx.x;
  const int qbase = blockIdx.x * QB;

  // ---- stage A: transpose [q][d] -> [d][q]; global reads coalesced ----
  for (int i = tid; i < QB * D; i += 256) {
    int q = i / D;
    int d = i - q * D;
    As[d * P + q] = kp[(qbase + q) * D + d];
  }
  // ---- stage B: tgt values + visibility mask, transposed ----
  for (int i = tid; i < T * D; i += 256) {
    int t = i / D;
    int d = i - t * D;
    float v = tgt[t * D + d];
    Bv[d * P + t] = v;
    Bm[d * P + t] = (v > 0.0f) ? 1.0f : 0.0f;
  }
  if (tid < T) Ids[tid] = ids[tid];
  __syncthreads();

  const int qg = tid >> 4;  // 0..15 -> q = qbase + 4*qg + i
  const int tg = tid & 15;  // 0..15 -> t = 4*tg + j

  float4 acc0 = make_float4(0.f, 0.f, 0.f, 0.f);
  float4 acc1 = acc0, acc2 = acc0, acc3 = acc0;

  const float4* As4 = (const float4*)As;
  const float4* Bv4 = (const float4*)Bv;
  const float4* Bm4 = (const float4*)Bm;

  for (int d = 0; d < D; ++d) {
    float4 a  = As4[d * P4 + qg];
    float4 bv = Bv4[d * P4 + tg];
    float4 bm = Bm4[d * P4 + tg];
#define ROW(acc, av)                         \
    acc.x += bm.x * fabsf((av) - bv.x);      \
    acc.y += bm.y * fabsf((av) - bv.y);      \
    acc.z += bm.z * fabsf((av) - bv.z);      \
    acc.w += bm.w * fabsf((av) - bv.w);
    ROW(acc0, a.x)
    ROW(acc1, a.y)
    ROW(acc2, a.z)
    ROW(acc3, a.w)
#undef ROW
  }

  // ---- epilogue: add focal class cost, write coalesced float4 ----
  const int t0 = tg * 4;
  int id0 = min(max(Ids[t0 + 0], 0), 1);
  int id1 = min(max(Ids[t0 + 1], 0), 1);
  int id2 = min(max(Ids[t0 + 2], 0), 1);
  int id3 = min(max(Ids[t0 + 3], 0), 1);

  float4 accs[4] = {acc0, acc1, acc2, acc3};
#pragma unroll
  for (int i = 0; i < 4; ++i) {
    int q = qbase + qg * 4 + i;
    float cc0 = focal_cost(logits[q * 2 + 0]);
    float cc1 = focal_cost(logits[q * 2 + 1]);
    float cc[2] = {cc0, cc1};
    float4 r;
    r.x = accs[i].x + cc[id0];
    r.y = accs[i].y + cc[id1];
    r.z = accs[i].z + cc[id2];
    r.w = accs[i].w + cc[id3];
    *(float4*)&out[q * T + t0] = r;
  }
}

extern "C" void kernel_launch(void* const* d_in, const int* in_sizes, int n_in,
                              void* d_out, int out_size, void* d_ws, size_t ws_size,
                              hipStream_t stream) {
  const float* logits = (const float*)d_in[0];
  const float* kp     = (const float*)d_in[1];
  const float* tgt    = (const float*)d_in[2];
  const int*   ids    = (const int*)d_in[3];
  float* out = (float*)d_out;

  matcher_kernel<<<dim3(Q / QB), dim3(256), 0, stream>>>(logits, kp, tgt, ids, out);
}

// Round 2
// 71.102 us; speedup vs baseline: 1.0013x; 1.0013x over previous
//
#include <hip/hip_runtime.h>

// HungarianMatcher cost kernel.
// C[q,t] = sum_d mask[t,d]*|kp[q,d]-tgt[t,d]| + (pos-neg)[q, ids[t]]
// Q=16384, T=64, D=63, C=2 classes.
//
// Design: GEMM-style tiling. Block = 64q x 64t (all targets), 256 threads,
// thread tile 4q x 4t. LDS holds transposed [d][q] / [d][t] tiles with
// pitch 68 floats (17 float4) -> conflict-free b128 reads in the main loop
// (A: 4 addrs x 16-lane broadcast; B: 16 addrs, 2-way aliasing = free).
// mask staged as 0/1 float so inner op is v_sub + v_fma(abs) = 2 VALU/elem.
//
// R2 change: #pragma unroll 7 on the d-loop. Trip count 63 is compile-time;
// full unroll hoists ~189 ds_read_b128 results -> VGPR spill (suspected
// cause of the ~25us observed vs 3.8us LDS floor). 7 iters keeps ~120 VGPRs.

#define ALPHA 0.25f
#define EPS 1e-8f

constexpr int Q  = 16 * 1024;  // bs*nq
constexpr int T  = 64;
constexpr int D  = 63;
constexpr int QB = 64;         // q rows per block
constexpr int P  = 68;         // LDS pitch in floats (17 float4s)
constexpr int P4 = 17;

__device__ inline float focal_cost(float x) {
  float p   = 1.0f / (1.0f + __expf(-x));
  float pos = ALPHA * (1.0f - p) * (1.0f - p) * (-__logf(p + EPS));
  float neg = (1.0f - ALPHA) * p * p * (-__logf(1.0f - p + EPS));
  return pos - neg;
}

__global__ __launch_bounds__(256) void matcher_kernel(
    const float* __restrict__ logits,  // [Q,2]
    const float* __restrict__ kp,      // [Q,63]
    const float* __restrict__ tgt,     // [64,63]
    const int*   __restrict__ ids,     // [64]
    float* __restrict__ out)           // [Q,64]
{
  __shared__ __align__(16) float As[64 * P];  // [d][q]  (row d, col q)
  __shared__ __align__(16) float Bv[64 * P];  // [d][t]
  __shared__ __align__(16) float Bm[64 * P];  // [d][t] mask 0/1
  __shared__ int Ids[T];

  const int tid   = threadIdx.x;
  const int qbase = blockIdx.x * QB;

  // ---- stage A: transpose [q][d] -> [d][q]; global reads coalesced ----
  for (int i = tid; i < QB * D; i += 256) {
    int q = i / D;
    int d = i - q * D;
    As[d * P + q] = kp[(qbase + q) * D + d];
  }
  // ---- stage B: tgt values + visibility mask, transposed ----
  for (int i = tid; i < T * D; i += 256) {
    int t = i / D;
    int d = i - t * D;
    float v = tgt[t * D + d];
    Bv[d * P + t] = v;
    Bm[d * P + t] = (v > 0.0f) ? 1.0f : 0.0f;
  }
  if (tid < T) Ids[tid] = ids[tid];
  __syncthreads();

  const int qg = tid >> 4;  // 0..15 -> q = qbase + 4*qg + i
  const int tg = tid & 15;  // 0..15 -> t = 4*tg + j

  float4 acc0 = make_float4(0.f, 0.f, 0.f, 0.f);
  float4 acc1 = acc0, acc2 = acc0, acc3 = acc0;

  const float4* As4 = (const float4*)As;
  const float4* Bv4 = (const float4*)Bv;
  const float4* Bm4 = (const float4*)Bm;

#pragma unroll 7
  for (int d = 0; d < D; ++d) {
    float4 a  = As4[d * P4 + qg];
    float4 bv = Bv4[d * P4 + tg];
    float4 bm = Bm4[d * P4 + tg];
#define ROW(acc, av)                         \
    acc.x += bm.x * fabsf((av) - bv.x);      \
    acc.y += bm.y * fabsf((av) - bv.y);      \
    acc.z += bm.z * fabsf((av) - bv.z);      \
    acc.w += bm.w * fabsf((av) - bv.w);
    ROW(acc0, a.x)
    ROW(acc1, a.y)
    ROW(acc2, a.z)
    ROW(acc3, a.w)
#undef ROW
  }

  // ---- epilogue: add focal class cost, write coalesced float4 ----
  const int t0 = tg * 4;
  int id0 = min(max(Ids[t0 + 0], 0), 1);
  int id1 = min(max(Ids[t0 + 1], 0), 1);
  int id2 = min(max(Ids[t0 + 2], 0), 1);
  int id3 = min(max(Ids[t0 + 3], 0), 1);

  float4 accs[4] = {acc0, acc1, acc2, acc3};
#pragma unroll
  for (int i = 0; i < 4; ++i) {
    int q = qbase + qg * 4 + i;
    float cc0 = focal_cost(logits[q * 2 + 0]);
    float cc1 = focal_cost(logits[q * 2 + 1]);
    float cc[2] = {cc0, cc1};
    float4 r;
    r.x = accs[i].x + cc[id0];
    r.y = accs[i].y + cc[id1];
    r.z = accs[i].z + cc[id2];
    r.w = accs[i].w + cc[id3];
    *(float4*)&out[q * T + t0] = r;
  }
}

extern "C" void kernel_launch(void* const* d_in, const int* in_sizes, int n_in,
                              void* d_out, int out_size, void* d_ws, size_t ws_size,
                              hipStream_t stream) {
  const float* logits = (const float*)d_in[0];
  const float* kp     = (const float*)d_in[1];
  const float* tgt    = (const float*)d_in[2];
  const int*   ids    = (const int*)d_in[3];
  float* out = (float*)d_out;

  matcher_kernel<<<dim3(Q / QB), dim3(256), 0, stream>>>(logits, kp, tgt, ids, out);
}